// Round 10
// baseline (76.664 us; speedup 1.0000x reference)
//
#include <hip/hip_runtime.h>
#include <cstdint>
#include <cmath>

#define N_ROWS 8192
#define N_COLS 2048
#define OUT_SPIKES_ELEMS (N_ROWS * N_COLS)

__host__ __device__ inline uint32_t rotl32(uint32_t x, int d) {
#if defined(__HIP_DEVICE_COMPILE__)
  return __builtin_amdgcn_alignbit(x, x, 32u - (uint32_t)d);  // v_alignbit_b32
#else
  return (x << d) | (x >> (32 - d));
#endif
}

// Exact replication of JAX's threefry2x32 (20 rounds, 5 key injections).
__host__ __device__ inline void threefry2x32(uint32_t k0, uint32_t k1,
                                             uint32_t x0, uint32_t x1,
                                             uint32_t& o0, uint32_t& o1) {
  const uint32_t ks2 = k0 ^ k1 ^ 0x1BD11BDAu;
  x0 += k0; x1 += k1;
#define TFR(r) { x0 += x1; x1 = rotl32(x1, (r)); x1 ^= x0; }
  TFR(13) TFR(15) TFR(26) TFR(6)
  x0 += k1; x1 += ks2 + 1u;
  TFR(17) TFR(29) TFR(16) TFR(24)
  x0 += ks2; x1 += k0 + 2u;
  TFR(13) TFR(15) TFR(26) TFR(6)
  x0 += k0; x1 += k1 + 3u;
  TFR(17) TFR(29) TFR(16) TFR(24)
  x0 += k1; x1 += ks2 + 4u;
  TFR(13) TFR(15) TFR(26) TFR(6)
  x0 += ks2; x1 += k0 + 5u;
#undef TFR
  o0 = x0; o1 = x1;
}

__device__ inline uint32_t random_bits32(uint32_t k0, uint32_t k1, uint32_t j) {
  uint32_t o0, o1;
  threefry2x32(k0, k1, 0u, j, o0, o1);
  return o0 ^ o1;
}

// bits -> [0,1) float exactly as jax.random.uniform does
__device__ inline float unit_from_bits(uint32_t bits) {
  return __uint_as_float((bits >> 9) | 0x3f800000u) - 1.0f;
}

// XLA's ErfInv32 expansion (Giles polynomial), non-contracted f32 ops.
__device__ inline float xla_erfinv(float x) {
  float w = -log1pf(__fmul_rn(-x, x));
  float p;
  if (w < 5.0f) {
    w = __fadd_rn(w, -2.5f);
    p = 2.81022636e-08f;
    p = __fadd_rn(3.43273939e-07f,  __fmul_rn(p, w));
    p = __fadd_rn(-3.5233877e-06f,  __fmul_rn(p, w));
    p = __fadd_rn(-4.39150654e-06f, __fmul_rn(p, w));
    p = __fadd_rn(0.00021858087f,   __fmul_rn(p, w));
    p = __fadd_rn(-0.00125372503f,  __fmul_rn(p, w));
    p = __fadd_rn(-0.00417768164f,  __fmul_rn(p, w));
    p = __fadd_rn(0.246640727f,     __fmul_rn(p, w));
    p = __fadd_rn(1.50140941f,      __fmul_rn(p, w));
  } else {
    w = __fadd_rn(sqrtf(w), -3.0f);
    p = -0.000200214257f;
    p = __fadd_rn(0.000100950558f,  __fmul_rn(p, w));
    p = __fadd_rn(0.00134934322f,   __fmul_rn(p, w));
    p = __fadd_rn(-0.00367342844f,  __fmul_rn(p, w));
    p = __fadd_rn(0.00573950773f,   __fmul_rn(p, w));
    p = __fadd_rn(-0.0076224613f,   __fmul_rn(p, w));
    p = __fadd_rn(0.00943887047f,   __fmul_rn(p, w));
    p = __fadd_rn(1.00167406f,      __fmul_rn(p, w));
    p = __fadd_rn(2.83297682f,      __fmul_rn(p, w));
  }
  return __fmul_rn(p, x);
}

__device__ inline float normal_from_bits(uint32_t bits) {
  const float lo = -0.99999994f;  // nextafter(-1,0)
  float unit = unit_from_bits(bits);
  float t = __fadd_rn(__fmul_rn(unit, 2.0f), lo);
  t = fmaxf(lo, t);
  return __fmul_rn(1.4142135623730951f, xla_erfinv(t));
}

// Inhibition Euler-Maruyama update — exact round-1 float path, computed
// lazily (candidate lanes + tid0 only).
__device__ inline float compute_ih(const float* __restrict__ inhibition,
                                   int row, float csig,
                                   uint32_t kn0, uint32_t kn1) {
  float nrm = normal_from_bits(random_bits32(kn0, kn1, (uint32_t)row));
  return __fadd_rn(__fmul_rn(0.9f, inhibition[row]), __fmul_rn(csig, nrm));
}

__global__ __launch_bounds__(512, 8) void spike_kernel(
    const float* __restrict__ inputs, const float* __restrict__ inhibition,
    float* __restrict__ out, float csig,
    uint32_t kn0, uint32_t kn1, uint32_t ku0, uint32_t ku1,
    uint32_t kc0, uint32_t kc1) {
  const int row = blockIdx.x;
  const int tid = threadIdx.x;      // 0..511
  const int wid = tid >> 6;         // 0..7
  const float tiny = 1.17549435e-38f;
  const float ln2 = 0.69314718055994531f;
  const float log2e = 1.4426950408889634f;

  __shared__ float s_sum[8];
  __shared__ float s_cv[8];
  __shared__ int   s_ci[8];
  __shared__ int   s_final[2];

  // --- one float4 load per thread (coalesced, 4 contiguous cols) ---
  const float* rowp = inputs + (size_t)row * N_COLS;
  float4 a = reinterpret_cast<const float4*>(rowp)[tid];
  float xv[4] = {a.x, a.y, a.z, a.w};

  // --- phase A: inhibition-free fast gumbel + f32 exp-sum; all in regs ---
  uint32_t bits4[4];
  float vhat4[4];
  float vmaxA = -INFINITY, vmaxB = -INFINITY;
  float tsA = 0.0f, tsB = 0.0f;
  const uint32_t jbase = (uint32_t)(row * N_COLS + 4 * tid);

#pragma unroll
  for (int k = 0; k < 4; ++k) {
    uint32_t bits = random_bits32(kc0, kc1, jbase + (uint32_t)k);
    float u = unit_from_bits(bits);
    float t = __fadd_rn(u, tiny);
    // fast gumbel: 2x v_log_f32 + 2 muls; |fast-exact| <= ~2e-5
    float w = __fmul_rn(-ln2, __log2f(t));
    float g = __fmul_rn(-ln2, __log2f(w));
    float v = __fadd_rn(g, xv[k]);  // NO ih — uniform shift cancels in argmax
    bits4[k] = bits; vhat4[k] = v;
    float e = __builtin_amdgcn_exp2f(__fmul_rn(xv[k], log2e));
    if (k & 1) { vmaxB = fmaxf(vmaxB, v); tsB += e; }
    else       { vmaxA = fmaxf(vmaxA, v); tsA += e; }
  }
  const float tmax = fmaxf(vmaxA, vmaxB);  // per-thread max (phase-B gate)
  float vmax = tmax;
  float tsum = tsA + tsB;

  // --- wave butterfly reduce (all lanes get result) ---
#pragma unroll
  for (int off = 32; off > 0; off >>= 1) {
    tsum += __shfl_xor(tsum, off);
    vmax = fmaxf(vmax, __shfl_xor(vmax, off));
  }
  const float thrM = __fsub_rn(vmax, 1e-3f);  // per-WAVE margin >> fast error

  // --- phase B: exact ocml path only for near-max candidates (~1/wave) ---
  float cval = -INFINITY;
  int   cidx = 0x7fffffff;
  if (tmax >= thrM) {
    float ih = compute_ih(inhibition, row, csig, kn0, kn1);
#pragma unroll
    for (int k = 0; k < 4; ++k) {
      if (vhat4[k] >= thrM) {
        int col = 4 * tid + k;
        float t = __fadd_rn(unit_from_bits(bits4[k]), tiny);
        float g = -logf(-logf(t));            // exact round-1 float path
        float x = __fsub_rn(rowp[col], ih);   // exact round-1 x (L1-hot)
        float v = __fadd_rn(g, x);
        if (v > cval || (v == cval && col < cidx)) { cval = v; cidx = col; }
      }
    }
  }

  // wave butterfly lex-argmax of exact candidates
#pragma unroll
  for (int off = 32; off > 0; off >>= 1) {
    float ov = __shfl_xor(cval, off);
    int   oi = __shfl_xor(cidx, off);
    if (ov > cval || (ov == cval && oi < cidx)) { cval = ov; cidx = oi; }
  }

  // --- single cross-wave combine (8 waves) ---
  if ((tid & 63) == 0) { s_sum[wid] = tsum; s_cv[wid] = cval; s_ci[wid] = cidx; }
  __syncthreads();

  if (tid == 0) {
    float T = 0.0f;
#pragma unroll
    for (int w = 0; w < 8; ++w) T += s_sum[w];
    float bv = s_cv[0];
    int   bi = s_ci[0];
#pragma unroll
    for (int w = 1; w < 8; ++w) {
      if (s_cv[w] > bv || (s_cv[w] == bv && s_ci[w] < bi)) { bv = s_cv[w]; bi = s_ci[w]; }
    }
    float ih = compute_ih(inhibition, row, csig, kn0, kn1);
    double total = (double)T * (double)expf(-ih);  // == sum exp(x-ih), ~1e-6 rel
    float urand = unit_from_bits(random_bits32(ku0, ku1, (uint32_t)row));
    float thr = __fmul_rn(0.001f, (float)total);
    int spike = (urand < thr) ? 1 : 0;
    s_final[0] = bi;
    s_final[1] = spike;
    out[OUT_SPIKES_ELEMS + row] = spike ? __fadd_rn(ih, 5.0f) : ih;
  }
  __syncthreads();

  // --- one-hot store: one float4 per thread ---
  const int bi = s_final[0];
  const int spike = s_final[1];
  const int col = 4 * tid;
  float4 z = make_float4(0.f, 0.f, 0.f, 0.f);
  if (spike && bi >= col && bi < col + 4) {
    (&z.x)[bi - col] = 1.0f;
  }
  *reinterpret_cast<float4*>(out + (size_t)row * N_COLS + col) = z;
}

extern "C" void kernel_launch(void* const* d_in, const int* in_sizes, int n_in,
                              void* d_out, int out_size, void* d_ws, size_t ws_size,
                              hipStream_t stream) {
  const float* inputs     = (const float*)d_in[0];
  const float* inhibition = (const float*)d_in[1];
  float* out = (float*)d_out;

  uint32_t kn0, kn1, ku0, ku1, kc0, kc1;
  threefry2x32(0u, 42u, 0u, 0u, kn0, kn1);
  threefry2x32(0u, 42u, 0u, 1u, ku0, ku1);
  threefry2x32(0u, 42u, 0u, 2u, kc0, kc1);

  const float csig = (float)(5.0 * sqrt(0.001));

  dim3 grid(N_ROWS), block(512);
  hipLaunchKernelGGL(spike_kernel, grid, block, 0, stream,
                     inputs, inhibition, out, csig,
                     kn0, kn1, ku0, ku1, kc0, kc1);
}

// Round 11
// 57.254 us; speedup vs baseline: 1.3390x; 1.3390x over previous
//
#include <hip/hip_runtime.h>
#include <cstdint>
#include <cmath>

#define N_ROWS 8192
#define N_COLS 2048
#define OUT_SPIKES_ELEMS (N_ROWS * N_COLS)

__host__ __device__ inline uint32_t rotl32(uint32_t x, int d) {
#if defined(__HIP_DEVICE_COMPILE__)
  return __builtin_amdgcn_alignbit(x, x, 32u - (uint32_t)d);  // v_alignbit_b32
#else
  return (x << d) | (x >> (32 - d));
#endif
}

// Exact replication of JAX's threefry2x32 (20 rounds, 5 key injections).
__host__ __device__ inline void threefry2x32(uint32_t k0, uint32_t k1,
                                             uint32_t x0, uint32_t x1,
                                             uint32_t& o0, uint32_t& o1) {
  const uint32_t ks2 = k0 ^ k1 ^ 0x1BD11BDAu;
  x0 += k0; x1 += k1;
#define TFR(r) { x0 += x1; x1 = rotl32(x1, (r)); x1 ^= x0; }
  TFR(13) TFR(15) TFR(26) TFR(6)
  x0 += k1; x1 += ks2 + 1u;
  TFR(17) TFR(29) TFR(16) TFR(24)
  x0 += ks2; x1 += k0 + 2u;
  TFR(13) TFR(15) TFR(26) TFR(6)
  x0 += k0; x1 += k1 + 3u;
  TFR(17) TFR(29) TFR(16) TFR(24)
  x0 += k1; x1 += ks2 + 4u;
  TFR(13) TFR(15) TFR(26) TFR(6)
  x0 += ks2; x1 += k0 + 5u;
#undef TFR
  o0 = x0; o1 = x1;
}

__device__ inline uint32_t random_bits32(uint32_t k0, uint32_t k1, uint32_t j) {
  uint32_t o0, o1;
  threefry2x32(k0, k1, 0u, j, o0, o1);
  return o0 ^ o1;
}

// bits -> [0,1) float exactly as jax.random.uniform does
__device__ inline float unit_from_bits(uint32_t bits) {
  return __uint_as_float((bits >> 9) | 0x3f800000u) - 1.0f;
}

// XLA's ErfInv32 expansion (Giles polynomial), non-contracted f32 ops.
__device__ inline float xla_erfinv(float x) {
  float w = -log1pf(__fmul_rn(-x, x));
  float p;
  if (w < 5.0f) {
    w = __fadd_rn(w, -2.5f);
    p = 2.81022636e-08f;
    p = __fadd_rn(3.43273939e-07f,  __fmul_rn(p, w));
    p = __fadd_rn(-3.5233877e-06f,  __fmul_rn(p, w));
    p = __fadd_rn(-4.39150654e-06f, __fmul_rn(p, w));
    p = __fadd_rn(0.00021858087f,   __fmul_rn(p, w));
    p = __fadd_rn(-0.00125372503f,  __fmul_rn(p, w));
    p = __fadd_rn(-0.00417768164f,  __fmul_rn(p, w));
    p = __fadd_rn(0.246640727f,     __fmul_rn(p, w));
    p = __fadd_rn(1.50140941f,      __fmul_rn(p, w));
  } else {
    w = __fadd_rn(sqrtf(w), -3.0f);
    p = -0.000200214257f;
    p = __fadd_rn(0.000100950558f,  __fmul_rn(p, w));
    p = __fadd_rn(0.00134934322f,   __fmul_rn(p, w));
    p = __fadd_rn(-0.00367342844f,  __fmul_rn(p, w));
    p = __fadd_rn(0.00573950773f,   __fmul_rn(p, w));
    p = __fadd_rn(-0.0076224613f,   __fmul_rn(p, w));
    p = __fadd_rn(0.00943887047f,   __fmul_rn(p, w));
    p = __fadd_rn(1.00167406f,      __fmul_rn(p, w));
    p = __fadd_rn(2.83297682f,      __fmul_rn(p, w));
  }
  return __fmul_rn(p, x);
}

__device__ inline float normal_from_bits(uint32_t bits) {
  const float lo = -0.99999994f;  // nextafter(-1,0)
  float unit = unit_from_bits(bits);
  float t = __fadd_rn(__fmul_rn(unit, 2.0f), lo);
  t = fmaxf(lo, t);
  return __fmul_rn(1.4142135623730951f, xla_erfinv(t));
}

// --- setup kernel: per-row {ih, exp(-ih), urand} into ws (float4/row) ---
__global__ __launch_bounds__(256) void row_setup_kernel(
    const float* __restrict__ inhibition, float* __restrict__ ws, float csig,
    uint32_t kn0, uint32_t kn1, uint32_t ku0, uint32_t ku1) {
  int r = blockIdx.x * 256 + threadIdx.x;
  if (r >= N_ROWS) return;
  // ih: exact round-1 float path
  float nrm = normal_from_bits(random_bits32(kn0, kn1, (uint32_t)r));
  float ih = __fadd_rn(__fmul_rn(0.9f, inhibition[r]), __fmul_rn(csig, nrm));
  float pre = expf(-ih);                                   // ocml, as round 9/10
  float ur  = unit_from_bits(random_bits32(ku0, ku1, (uint32_t)r));
  reinterpret_cast<float4*>(ws)[r] = make_float4(ih, pre, ur, 0.0f);
}

__global__ __launch_bounds__(256, 6) void spike_kernel(
    const float* __restrict__ inputs, const float* __restrict__ ws,
    float* __restrict__ out, uint32_t kc0, uint32_t kc1) {
  const int row = blockIdx.x;
  const int tid = threadIdx.x;
  const int wid = tid >> 6;
  const float tiny = 1.17549435e-38f;
  const float nln2 = -0.69314718055994531f;
  const float log2e = 1.4426950408889634f;

  // packed per-element stash {bits, vhat}: b64 ops, conflict-free stride
  __shared__ uint2 stash[8 * 256];   // 16 KB
  __shared__ float s_sum[4];
  __shared__ float s_cv[4];
  __shared__ int   s_ci[4];
  __shared__ int   s_final[2];

  // --- issue both global loads up front ---
  const float* rowp = inputs + (size_t)row * N_COLS;
  const float4* rowp4 = reinterpret_cast<const float4*>(rowp);
  float4 a0 = rowp4[tid];
  float4 a1 = rowp4[tid + 256];
  float xv[8] = {a0.x, a0.y, a0.z, a0.w, a1.x, a1.y, a1.z, a1.w};

  // --- phase A: shifted fast gumbel (constant C dropped — argmax-invariant),
  //     inhibition-free (uniform -ih shift cancels), f32 dual-acc sums ---
  float vmaxA = -INFINITY, vmaxB = -INFINITY;
  float tsA = 0.0f, tsB = 0.0f;
  const uint32_t jbase = (uint32_t)(row * N_COLS + 4 * tid);

#pragma unroll
  for (int i8 = 0; i8 < 8; ++i8) {
    const uint32_t j = jbase + (uint32_t)((i8 & 3) + 1024 * (i8 >> 2));
    uint32_t bits = random_bits32(kc0, kc1, j);
    float u = unit_from_bits(bits);
    float t = __fadd_rn(u, tiny);
    float m = __log2f(t);                      // m < 0
    float v = fmaf(nln2, __log2f(-m), xv[i8]); // v = -ln2*log2(-log2 t) + x
    stash[i8 * 256 + tid] = make_uint2(bits, __float_as_uint(v));
    float e = __builtin_amdgcn_exp2f(__fmul_rn(xv[i8], log2e));
    if (i8 & 1) { vmaxB = fmaxf(vmaxB, v); tsB += e; }
    else        { vmaxA = fmaxf(vmaxA, v); tsA += e; }
  }
  const float tmax = fmaxf(vmaxA, vmaxB);  // per-thread max (phase-B gate)
  float vmax = tmax;
  float tsum = tsA + tsB;

  // --- wave butterfly reduce (all lanes get result) ---
#pragma unroll
  for (int off = 32; off > 0; off >>= 1) {
    tsum += __shfl_xor(tsum, off);
    vmax = fmaxf(vmax, __shfl_xor(vmax, off));
  }
  const float thrM = __fsub_rn(vmax, 1e-3f);  // margin >> 4e-5 fast-log error

  // --- phase B: exact ocml path only for near-max candidates (~1/wave) ---
  float cval = -INFINITY;
  int   cidx = 0x7fffffff;
  if (tmax >= thrM) {
    float ih = ws[4 * row];   // precomputed exact ih
#pragma unroll
    for (int i8 = 0; i8 < 8; ++i8) {
      uint2 s = stash[i8 * 256 + tid];
      if (__uint_as_float(s.y) >= thrM) {
        int col = 4 * tid + 1024 * (i8 >> 2) + (i8 & 3);
        float t = __fadd_rn(unit_from_bits(s.x), tiny);
        float g = -logf(-logf(t));            // exact round-1 float path
        float x = __fsub_rn(rowp[col], ih);   // exact round-1 x (L1-hot)
        float v = __fadd_rn(g, x);
        if (v > cval || (v == cval && col < cidx)) { cval = v; cidx = col; }
      }
    }
  }

  // wave butterfly lex-argmax of exact candidates
#pragma unroll
  for (int off = 32; off > 0; off >>= 1) {
    float ov = __shfl_xor(cval, off);
    int   oi = __shfl_xor(cidx, off);
    if (ov > cval || (ov == cval && oi < cidx)) { cval = ov; cidx = oi; }
  }

  // --- single cross-wave combine ---
  if ((tid & 63) == 0) { s_sum[wid] = tsum; s_cv[wid] = cval; s_ci[wid] = cidx; }
  __syncthreads();

  if (tid == 0) {
    float T = s_sum[0] + s_sum[1] + s_sum[2] + s_sum[3];
    float bv = s_cv[0];
    int   bi = s_ci[0];
    for (int w = 1; w < 4; ++w) {
      if (s_cv[w] > bv || (s_cv[w] == bv && s_ci[w] < bi)) { bv = s_cv[w]; bi = s_ci[w]; }
    }
    float4 wsd = reinterpret_cast<const float4*>(ws)[row];
    double total = (double)T * (double)wsd.y;   // == sum exp(x-ih), ~1e-6 rel
    float thr = __fmul_rn(0.001f, (float)total);
    int spike = (wsd.z < thr) ? 1 : 0;
    s_final[0] = bi;
    s_final[1] = spike;
    out[OUT_SPIKES_ELEMS + row] = spike ? __fadd_rn(wsd.x, 5.0f) : wsd.x;
  }
  __syncthreads();

  // --- one-hot store: two float4 per thread ---
  const int bi = s_final[0];
  const int spike = s_final[1];
  float* orow = out + (size_t)row * N_COLS;
#pragma unroll
  for (int ch = 0; ch < 2; ++ch) {
    const int col = 4 * tid + 1024 * ch;
    float4 z = make_float4(0.f, 0.f, 0.f, 0.f);
    if (spike && bi >= col && bi < col + 4) {
      (&z.x)[bi - col] = 1.0f;
    }
    *reinterpret_cast<float4*>(orow + col) = z;
  }
}

extern "C" void kernel_launch(void* const* d_in, const int* in_sizes, int n_in,
                              void* d_out, int out_size, void* d_ws, size_t ws_size,
                              hipStream_t stream) {
  const float* inputs     = (const float*)d_in[0];
  const float* inhibition = (const float*)d_in[1];
  float* out = (float*)d_out;
  float* ws  = (float*)d_ws;   // needs 8192 * 16 B = 128 KiB

  uint32_t kn0, kn1, ku0, ku1, kc0, kc1;
  threefry2x32(0u, 42u, 0u, 0u, kn0, kn1);
  threefry2x32(0u, 42u, 0u, 1u, ku0, ku1);
  threefry2x32(0u, 42u, 0u, 2u, kc0, kc1);

  const float csig = (float)(5.0 * sqrt(0.001));

  hipLaunchKernelGGL(row_setup_kernel, dim3(N_ROWS / 256), dim3(256), 0, stream,
                     inhibition, ws, csig, kn0, kn1, ku0, ku1);
  hipLaunchKernelGGL(spike_kernel, dim3(N_ROWS), dim3(256), 0, stream,
                     inputs, ws, out, kc0, kc1);
}

// Round 12
// 49.427 us; speedup vs baseline: 1.5511x; 1.1584x over previous
//
#include <hip/hip_runtime.h>
#include <cstdint>
#include <cmath>

#define N_ROWS 8192
#define N_COLS 2048
#define OUT_SPIKES_ELEMS (N_ROWS * N_COLS)

__host__ __device__ inline uint32_t rotl32(uint32_t x, int d) {
#if defined(__HIP_DEVICE_COMPILE__)
  return __builtin_amdgcn_alignbit(x, x, 32u - (uint32_t)d);  // v_alignbit_b32
#else
  return (x << d) | (x >> (32 - d));
#endif
}

// Exact replication of JAX's threefry2x32 (20 rounds, 5 key injections).
__host__ __device__ inline void threefry2x32(uint32_t k0, uint32_t k1,
                                             uint32_t x0, uint32_t x1,
                                             uint32_t& o0, uint32_t& o1) {
  const uint32_t ks2 = k0 ^ k1 ^ 0x1BD11BDAu;
  x0 += k0; x1 += k1;
#define TFR(r) { x0 += x1; x1 = rotl32(x1, (r)); x1 ^= x0; }
  TFR(13) TFR(15) TFR(26) TFR(6)
  x0 += k1; x1 += ks2 + 1u;
  TFR(17) TFR(29) TFR(16) TFR(24)
  x0 += ks2; x1 += k0 + 2u;
  TFR(13) TFR(15) TFR(26) TFR(6)
  x0 += k0; x1 += k1 + 3u;
  TFR(17) TFR(29) TFR(16) TFR(24)
  x0 += k1; x1 += ks2 + 4u;
  TFR(13) TFR(15) TFR(26) TFR(6)
  x0 += ks2; x1 += k0 + 5u;
#undef TFR
  o0 = x0; o1 = x1;
}

__device__ inline uint32_t random_bits32(uint32_t k0, uint32_t k1, uint32_t j) {
  uint32_t o0, o1;
  threefry2x32(k0, k1, 0u, j, o0, o1);
  return o0 ^ o1;
}

// bits -> [0,1) float exactly as jax.random.uniform does
__device__ inline float unit_from_bits(uint32_t bits) {
  return __uint_as_float((bits >> 9) | 0x3f800000u) - 1.0f;
}

// XLA's ErfInv32 expansion (Giles polynomial), non-contracted f32 ops.
__device__ inline float xla_erfinv(float x) {
  float w = -log1pf(__fmul_rn(-x, x));
  float p;
  if (w < 5.0f) {
    w = __fadd_rn(w, -2.5f);
    p = 2.81022636e-08f;
    p = __fadd_rn(3.43273939e-07f,  __fmul_rn(p, w));
    p = __fadd_rn(-3.5233877e-06f,  __fmul_rn(p, w));
    p = __fadd_rn(-4.39150654e-06f, __fmul_rn(p, w));
    p = __fadd_rn(0.00021858087f,   __fmul_rn(p, w));
    p = __fadd_rn(-0.00125372503f,  __fmul_rn(p, w));
    p = __fadd_rn(-0.00417768164f,  __fmul_rn(p, w));
    p = __fadd_rn(0.246640727f,     __fmul_rn(p, w));
    p = __fadd_rn(1.50140941f,      __fmul_rn(p, w));
  } else {
    w = __fadd_rn(sqrtf(w), -3.0f);
    p = -0.000200214257f;
    p = __fadd_rn(0.000100950558f,  __fmul_rn(p, w));
    p = __fadd_rn(0.00134934322f,   __fmul_rn(p, w));
    p = __fadd_rn(-0.00367342844f,  __fmul_rn(p, w));
    p = __fadd_rn(0.00573950773f,   __fmul_rn(p, w));
    p = __fadd_rn(-0.0076224613f,   __fmul_rn(p, w));
    p = __fadd_rn(0.00943887047f,   __fmul_rn(p, w));
    p = __fadd_rn(1.00167406f,      __fmul_rn(p, w));
    p = __fadd_rn(2.83297682f,      __fmul_rn(p, w));
  }
  return __fmul_rn(p, x);
}

__device__ inline float normal_from_bits(uint32_t bits) {
  const float lo = -0.99999994f;  // nextafter(-1,0)
  float unit = unit_from_bits(bits);
  float t = __fadd_rn(__fmul_rn(unit, 2.0f), lo);
  t = fmaxf(lo, t);
  return __fmul_rn(1.4142135623730951f, xla_erfinv(t));
}

// --- DPP wave64 reductions (rocPRIM pattern), VALU pipe only ---
// sum: invalid/masked lanes contribute 0 (bound_ctrl=true, old=0)
__device__ __forceinline__ float wave_sum_bcast(float x) {
  x += __int_as_float(__builtin_amdgcn_update_dpp(0, __float_as_int(x), 0x111, 0xf, 0xf, true));
  x += __int_as_float(__builtin_amdgcn_update_dpp(0, __float_as_int(x), 0x112, 0xf, 0xf, true));
  x += __int_as_float(__builtin_amdgcn_update_dpp(0, __float_as_int(x), 0x114, 0xf, 0xf, true));
  x += __int_as_float(__builtin_amdgcn_update_dpp(0, __float_as_int(x), 0x118, 0xf, 0xf, true));
  x += __int_as_float(__builtin_amdgcn_update_dpp(0, __float_as_int(x), 0x142, 0xa, 0xf, true));
  x += __int_as_float(__builtin_amdgcn_update_dpp(0, __float_as_int(x), 0x143, 0xc, 0xf, true));
  return __int_as_float(__builtin_amdgcn_readlane(__float_as_int(x), 63));
}
// max: invalid/masked lanes return old=x -> fmax(x,x)=x (bound_ctrl=false)
__device__ __forceinline__ float wave_max_bcast(float x) {
  int xi;
  xi = __float_as_int(x);
  x = fmaxf(x, __int_as_float(__builtin_amdgcn_update_dpp(xi, xi, 0x111, 0xf, 0xf, false)));
  xi = __float_as_int(x);
  x = fmaxf(x, __int_as_float(__builtin_amdgcn_update_dpp(xi, xi, 0x112, 0xf, 0xf, false)));
  xi = __float_as_int(x);
  x = fmaxf(x, __int_as_float(__builtin_amdgcn_update_dpp(xi, xi, 0x114, 0xf, 0xf, false)));
  xi = __float_as_int(x);
  x = fmaxf(x, __int_as_float(__builtin_amdgcn_update_dpp(xi, xi, 0x118, 0xf, 0xf, false)));
  xi = __float_as_int(x);
  x = fmaxf(x, __int_as_float(__builtin_amdgcn_update_dpp(xi, xi, 0x142, 0xa, 0xf, false)));
  xi = __float_as_int(x);
  x = fmaxf(x, __int_as_float(__builtin_amdgcn_update_dpp(xi, xi, 0x143, 0xc, 0xf, false)));
  return __int_as_float(__builtin_amdgcn_readlane(__float_as_int(x), 63));
}

// --- setup kernel: per-row {ih, exp(-ih), urand} into ws (float4/row) ---
__global__ __launch_bounds__(256) void row_setup_kernel(
    const float* __restrict__ inhibition, float* __restrict__ ws, float csig,
    uint32_t kn0, uint32_t kn1, uint32_t ku0, uint32_t ku1) {
  int r = blockIdx.x * 256 + threadIdx.x;
  if (r >= N_ROWS) return;
  float nrm = normal_from_bits(random_bits32(kn0, kn1, (uint32_t)r));
  float ih = __fadd_rn(__fmul_rn(0.9f, inhibition[r]), __fmul_rn(csig, nrm));
  float pre = expf(-ih);                                   // ocml, as round 9/11
  float ur  = unit_from_bits(random_bits32(ku0, ku1, (uint32_t)r));
  reinterpret_cast<float4*>(ws)[r] = make_float4(ih, pre, ur, 0.0f);
}

__global__ __launch_bounds__(256, 6) void spike_kernel(
    const float* __restrict__ inputs, const float* __restrict__ ws,
    float* __restrict__ out, uint32_t kc0, uint32_t kc1) {
  const int row = blockIdx.x;
  const int tid = threadIdx.x;
  const int wid = tid >> 6;
  const float tiny = 1.17549435e-38f;
  const float nln2 = -0.69314718055994531f;
  const float log2e = 1.4426950408889634f;

  // per-thread-private stash {bits, vhat}; stride-256 conflict-free b64 ops
  __shared__ uint2 stash[8 * 256];   // 16 KB
  __shared__ float s_sum[4];
  __shared__ unsigned long long s_best;

  if (tid == 0) s_best = 0ull;   // ordered before atomics by bar1

  // --- issue both global loads up front ---
  const float* rowp = inputs + (size_t)row * N_COLS;
  const float4* rowp4 = reinterpret_cast<const float4*>(rowp);
  float4 a0 = rowp4[tid];
  float4 a1 = rowp4[tid + 256];
  float xv[8] = {a0.x, a0.y, a0.z, a0.w, a1.x, a1.y, a1.z, a1.w};

  // --- phase A: shifted fast gumbel (const dropped — argmax-invariant),
  //     inhibition-free, f32 dual-acc sums ---
  float vmaxA = -INFINITY, vmaxB = -INFINITY;
  float tsA = 0.0f, tsB = 0.0f;
  const uint32_t jbase = (uint32_t)(row * N_COLS + 4 * tid);

#pragma unroll
  for (int i8 = 0; i8 < 8; ++i8) {
    const uint32_t j = jbase + (uint32_t)((i8 & 3) + 1024 * (i8 >> 2));
    uint32_t bits = random_bits32(kc0, kc1, j);
    float u = unit_from_bits(bits);
    float t = __fadd_rn(u, tiny);
    float m = __log2f(t);                      // m < 0
    float v = fmaf(nln2, __log2f(-m), xv[i8]); // shifted fast gumbel + x
    stash[i8 * 256 + tid] = make_uint2(bits, __float_as_uint(v));
    float e = __builtin_amdgcn_exp2f(__fmul_rn(xv[i8], log2e));
    if (i8 & 1) { vmaxB = fmaxf(vmaxB, v); tsB += e; }
    else        { vmaxA = fmaxf(vmaxA, v); tsA += e; }
  }
  const float tmax = fmaxf(vmaxA, vmaxB);  // per-thread max (phase-B gate)

  // --- DPP wave reductions (VALU pipe; no ds_bpermute) ---
  float tsum = wave_sum_bcast(tsA + tsB);
  float vmax = wave_max_bcast(tmax);
  if ((tid & 63) == 0) s_sum[wid] = tsum;
  const float thrM = __fsub_rn(vmax, 1e-3f);  // margin >> 4e-5 fast-log error

  __syncthreads();   // bar1: s_best init + s_sum visible; stash is thread-private

  // --- phase B: exact ocml path only for near-max candidates (~1/wave);
  //     block argmax via one packed-u64 LDS atomicMax (order-independent) ---
  if (tmax >= thrM) {
    float ih = ws[4 * row];   // precomputed exact ih
#pragma unroll
    for (int i8 = 0; i8 < 8; ++i8) {
      uint2 s = stash[i8 * 256 + tid];
      if (__uint_as_float(s.y) >= thrM) {
        int col = 4 * tid + 1024 * (i8 >> 2) + (i8 & 3);
        float t = __fadd_rn(unit_from_bits(s.x), tiny);
        float g = -logf(-logf(t));            // exact round-1 float path
        float x = __fsub_rn(rowp[col], ih);   // exact round-1 x (L1-hot)
        float v = __fadd_rn(g, x);
        uint32_t b = __float_as_uint(v);
        uint32_t key = (b & 0x80000000u) ? ~b : (b | 0x80000000u);
        unsigned long long pk =
            ((unsigned long long)key << 32) | (uint32_t)(~(uint32_t)col);
        atomicMax(&s_best, pk);   // ties -> larger ~col -> smaller col (first max)
      }
    }
  }

  __syncthreads();   // bar2: s_best final

  // --- parallel epilogue: every thread derives {bi, spike} identically ---
  const int bi = (int)(~(uint32_t)(s_best & 0xFFFFFFFFull));
  float T = ((s_sum[0] + s_sum[1]) + s_sum[2]) + s_sum[3];  // fixed order
  float4 wsd = reinterpret_cast<const float4*>(ws)[row];
  double total = (double)T * (double)wsd.y;   // == sum exp(x-ih), ~1e-6 rel
  float thr = __fmul_rn(0.001f, (float)total);
  const int spike = (wsd.z < thr) ? 1 : 0;
  if (tid == 0) out[OUT_SPIKES_ELEMS + row] = spike ? __fadd_rn(wsd.x, 5.0f) : wsd.x;

  // --- one-hot store: two float4 per thread ---
  float* orow = out + (size_t)row * N_COLS;
#pragma unroll
  for (int ch = 0; ch < 2; ++ch) {
    const int col = 4 * tid + 1024 * ch;
    float4 z = make_float4(0.f, 0.f, 0.f, 0.f);
    if (spike && bi >= col && bi < col + 4) {
      (&z.x)[bi - col] = 1.0f;
    }
    *reinterpret_cast<float4*>(orow + col) = z;
  }
}

extern "C" void kernel_launch(void* const* d_in, const int* in_sizes, int n_in,
                              void* d_out, int out_size, void* d_ws, size_t ws_size,
                              hipStream_t stream) {
  const float* inputs     = (const float*)d_in[0];
  const float* inhibition = (const float*)d_in[1];
  float* out = (float*)d_out;
  float* ws  = (float*)d_ws;   // 8192 * 16 B = 128 KiB

  uint32_t kn0, kn1, ku0, ku1, kc0, kc1;
  threefry2x32(0u, 42u, 0u, 0u, kn0, kn1);
  threefry2x32(0u, 42u, 0u, 1u, ku0, ku1);
  threefry2x32(0u, 42u, 0u, 2u, kc0, kc1);

  const float csig = (float)(5.0 * sqrt(0.001));

  hipLaunchKernelGGL(row_setup_kernel, dim3(N_ROWS / 256), dim3(256), 0, stream,
                     inhibition, ws, csig, kn0, kn1, ku0, ku1);
  hipLaunchKernelGGL(spike_kernel, dim3(N_ROWS), dim3(256), 0, stream,
                     inputs, ws, out, kc0, kc1);
}